// Round 15
// baseline (1383.439 us; speedup 1.0000x reference)
//
#include <hip/hip_runtime.h>
#include <hip/hip_bf16.h>

#define NBATCH 256
#define TSE 168
#define TSD 24
#define NTOK (NBATCH*TSE)   // 43008
#define NDTOK (NBATCH*TSD)  // 6144

// packed bf16 MFMA-B-fragment offsets (ushort units, region base pk)
#define PK_VSN    0         // 9 x [K=128, NC=256]  = 294912
#define PK_GC1    294912    // [K=1152, NC=256]     = 294912
#define PK_GC2    589824    // [K=128, NC=256]      = 32768
#define PK_ENC0   622592    // [128,512]            = 65536
#define PK_ENC1   688128    // [128,512]            = 65536
#define PK_DEC0   753664    // [128,512]            = 65536
#define PK_DEC1   819200    // [128,512]            = 65536
#define PK_AIN    884736    // [128,384]            = 49152
#define PK_AOUT   933888    // [128,128]            = 16384
#define PK_PAF1   950272    // [128,128]            = 16384
#define PK_PAF2G  966656    // [128,256]            = 32768
#define PK_WHH_E0 999424    // [128,512]            = 65536
#define PK_WHH_E1 1064960
#define PK_WHH_D0 1130496
#define PK_WHH_D1 1196032
// pk total = 1,261,568 ushorts = 630,784 floats

typedef __attribute__((ext_vector_type(8))) short short8;
typedef __attribute__((ext_vector_type(4))) float f32x4;
typedef __attribute__((ext_vector_type(2))) __fp16 fp16x2;

__device__ __forceinline__ float sigm(float x){ return 1.f/(1.f + __expf(-x)); }
__device__ __forceinline__ float tanhx(float x){
  float cx = fminf(fmaxf(x, -15.f), 15.f);
  float e = __expf(2.f*cx);
  return (e-1.f)/(e+1.f);
}
__device__ __forceinline__ float eluf(float x){ return x > 0.f ? x : (__expf(x)-1.f); }
__device__ __forceinline__ unsigned short f2bu(float v){
  unsigned int u = __float_as_uint(v);
  u = (u + 0x7fffu + ((u>>16)&1u)) >> 16;
  return (unsigned short)u;
}
__device__ __forceinline__ unsigned short f2h(float x){
  union { _Float16 h; unsigned short u; } v;
  v.h = (_Float16)x; return v.u;
}
__device__ __forceinline__ float h2f(unsigned short u){
  union { unsigned short u; _Float16 h; } v;
  v.u = u; return (float)v.h;
}

// ---------------- pack weights into bf16 MFMA B-fragment order -------------
// dst layout: [ct][kc][lane(64)][j(8)], ct=n/16, kc=k/32, lane=(n%16)+16*((k%32)/8), j=k%8
__global__ __launch_bounds__(256) void k_pack(
    const float* __restrict__ s0, const float* __restrict__ s1,
    unsigned short* __restrict__ dst, int K, int NC, int nsplit,
    int s0bs, int s1bs, int dstbs)
{
  int id = blockIdx.x*256 + threadIdx.x;
  if (id >= K*NC) return;
  int by = blockIdx.y;
  int n = id / K, k = id - n*K;
  float v = (n < nsplit) ? s0[(size_t)by*s0bs + (size_t)n*K + k]
                         : s1[(size_t)by*s1bs + (size_t)(n-nsplit)*K + k];
  int ct = n >> 4, kc = k >> 5;
  int lane = (n & 15) | (((k >> 3) & 3) << 4);
  int j = k & 7;
  int KC = K >> 5;
  dst[(size_t)by*dstbs + (((size_t)ct*KC + kc)*64 + lane)*8 + j] = f2bu(v);
}

// ---------------- VSN per-feature GRN (MFMA) -> proc2 chunk-major bf16 -----
__global__ __launch_bounds__(256) void k_vsn_mfma(
    const float* __restrict__ x, const float* __restrict__ fc1_w, const float* __restrict__ fc1_b,
    const unsigned short* __restrict__ pk, const float* __restrict__ fc2_b,
    const float* __restrict__ gate_b, const float* __restrict__ skip_w,
    const float* __restrict__ skip_b, const float* __restrict__ ln_g,
    const float* __restrict__ ln_b, unsigned short* __restrict__ proc2)
{
  const int f = blockIdx.y;
  const int nb = blockIdx.x;
  const int n0 = nb * 64;
  const int tid = threadIdx.x;
  const int wv = tid >> 6, l = tid & 63;
  __shared__ __align__(16) unsigned short As[64*136];
  __shared__ float xs[64];
  __shared__ float vbuf[64*129];
  __shared__ float red[64][4][2];
  __shared__ float mr[64][2];
  if (tid < 64) xs[tid] = x[(size_t)(n0+tid)*9 + f];
  __syncthreads();
  { int i = tid & 127;
    float w1 = fc1_w[f*128 + i], b1 = fc1_b[f*128 + i];
    for (int it = 0; it < 32; it++) {
      int tk = (tid >> 7) + it*2;
      As[tk*136 + i] = f2bu(eluf(xs[tk]*w1 + b1));
    }
  }
  __syncthreads();
  const unsigned short* Wp = pk + PK_VSN + (size_t)f*32768;
  f32x4 acc[4][4];
  #pragma unroll
  for (int rt = 0; rt < 4; rt++)
    #pragma unroll
    for (int ci = 0; ci < 4; ci++) acc[rt][ci] = (f32x4)(0.f);
  #pragma unroll
  for (int kc = 0; kc < 4; kc++) {
    short8 af[4];
    #pragma unroll
    for (int rt = 0; rt < 4; rt++) {
      int row = rt*16 + (l & 15), g = kc*4 + (l >> 4);
      af[rt] = *(const short8*)&As[row*136 + g*8];
    }
    short8 bf[4];
    #pragma unroll
    for (int ci = 0; ci < 4; ci++) {
      int ct = (ci < 2) ? (wv*2 + ci) : (8 + wv*2 + (ci-2));
      bf[ci] = *(const short8*)&Wp[(((size_t)ct*4 + kc)*64 + l)*8];
    }
    #pragma unroll
    for (int rt = 0; rt < 4; rt++)
      #pragma unroll
      for (int ci = 0; ci < 4; ci++)
        acc[rt][ci] = __builtin_amdgcn_mfma_f32_16x16x32_bf16(af[rt], bf[ci], acc[rt][ci], 0, 0, 0);
  }
  __syncthreads();
  #pragma unroll
  for (int ci = 0; ci < 2; ci++) {
    int ch = wv*32 + ci*16 + (l & 15);
    float fb = fc2_b[f*128 + ch], gb = gate_b[f*128 + ch];
    float sw = skip_w[f*128 + ch], sb = skip_b[f*128 + ch];
    #pragma unroll
    for (int rt = 0; rt < 4; rt++)
      #pragma unroll
      for (int r = 0; r < 4; r++) {
        int row = rt*16 + (l >> 4)*4 + r;
        float hv = acc[rt][ci][r] + fb;
        float gv = sigm(acc[rt][ci+2][r] + gb);
        float sv = xs[row]*sw + sb;
        vbuf[row*129 + ch] = sv + hv*gv;
      }
  }
  __syncthreads();
  { int tk = tid >> 2, q = tid & 3;
    float s1 = 0.f, s2 = 0.f;
    #pragma unroll
    for (int i = 0; i < 32; i++) { float z = vbuf[tk*129 + q*32 + i]; s1 += z; s2 += z*z; }
    red[tk][q][0] = s1; red[tk][q][1] = s2;
  }
  __syncthreads();
  if ((tid & 3) == 0) {
    int tk = tid >> 2;
    float a = 0.f, b2 = 0.f;
    for (int p = 0; p < 4; p++) { a += red[tk][p][0]; b2 += red[tk][p][1]; }
    float mean = a * 0.0078125f;
    float var = b2 * 0.0078125f - mean*mean;
    mr[tk][0] = mean; mr[tk][1] = rsqrtf(fmaxf(var, 0.f) + 1e-5f);
  }
  __syncthreads();
  { int i = tid & 127;
    float lg = ln_g[f*128 + i], lb = ln_b[f*128 + i];
    size_t base = ((size_t)nb*9 + f)*8192;
    for (int it = 0; it < 32; it++) {
      int tk = (tid >> 7) + it*2;
      float z = (vbuf[tk*129 + i] - mr[tk][0]) * mr[tk][1] * lg + lb;
      proc2[base + tk*128 + i] = f2bu(z);
    }
  }
}

// ---------------- grand-selection GRN (MFMA, fully fused) -> sel bf16 ------
__global__ __launch_bounds__(256) void k_gc_mfma(
    const unsigned short* __restrict__ proc2, const unsigned short* __restrict__ pk,
    const float* __restrict__ fc1_b, const float* __restrict__ fc2_b,
    const float* __restrict__ gate_b, const float* __restrict__ skip_b,
    const float* __restrict__ ln_g, const float* __restrict__ ln_b,
    unsigned short* __restrict__ selb)
{
  const int nb = blockIdx.x;
  const int n0 = nb * 64;
  const int tid = threadIdx.x;
  const int wv = tid >> 6, l = tid & 63;
  __shared__ __align__(16) unsigned short As[64*136];
  __shared__ __align__(16) unsigned short A2s[64*136];
  __shared__ float vbuf[64*129];
  __shared__ float red[64][4][2];
  __shared__ float mr[64][2];
  const unsigned short* W1 = pk + PK_GC1;
  f32x4 acc1[4][4];
  #pragma unroll
  for (int rt = 0; rt < 4; rt++)
    #pragma unroll
    for (int ci = 0; ci < 4; ci++) acc1[rt][ci] = (f32x4)(0.f);
  for (int c = 0; c < 9; c++) {
    size_t cbase = ((size_t)nb*9 + c)*8192;
    #pragma unroll
    for (int i = 0; i < 4; i++) {
      int gi = i*256 + tid;
      int row = gi >> 4, g = gi & 15;
      uint4 v = *(const uint4*)(proc2 + cbase + row*128 + g*8);
      *(uint4*)&As[row*136 + g*8] = v;
    }
    __syncthreads();
    #pragma unroll
    for (int kc = 0; kc < 4; kc++) {
      int kk = c*4 + kc;
      short8 af[4];
      #pragma unroll
      for (int rt = 0; rt < 4; rt++) {
        int row = rt*16 + (l & 15), g = kc*4 + (l >> 4);
        af[rt] = *(const short8*)&As[row*136 + g*8];
      }
      short8 bf[4];
      #pragma unroll
      for (int ci = 0; ci < 4; ci++) {
        int ct = (ci < 2) ? (wv*2 + ci) : (8 + wv*2 + (ci-2));
        bf[ci] = *(const short8*)&W1[(((size_t)ct*36 + kk)*64 + l)*8];
      }
      #pragma unroll
      for (int rt = 0; rt < 4; rt++)
        #pragma unroll
        for (int ci = 0; ci < 4; ci++)
          acc1[rt][ci] = __builtin_amdgcn_mfma_f32_16x16x32_bf16(af[rt], bf[ci], acc1[rt][ci], 0, 0, 0);
    }
    __syncthreads();
  }
  #pragma unroll
  for (int ci = 0; ci < 2; ci++) {
    int ch = wv*32 + ci*16 + (l & 15);
    float fb = fc1_b[ch];
    #pragma unroll
    for (int rt = 0; rt < 4; rt++)
      #pragma unroll
      for (int r = 0; r < 4; r++) {
        int row = rt*16 + (l >> 4)*4 + r;
        A2s[row*136 + ch] = f2bu(eluf(acc1[rt][ci][r] + fb));
      }
  }
  __syncthreads();
  const unsigned short* W2 = pk + PK_GC2;
  f32x4 acc2[4][4];
  #pragma unroll
  for (int rt = 0; rt < 4; rt++)
    #pragma unroll
    for (int ci = 0; ci < 4; ci++) acc2[rt][ci] = (f32x4)(0.f);
  #pragma unroll
  for (int kc = 0; kc < 4; kc++) {
    short8 af[4];
    #pragma unroll
    for (int rt = 0; rt < 4; rt++) {
      int row = rt*16 + (l & 15), g = kc*4 + (l >> 4);
      af[rt] = *(const short8*)&A2s[row*136 + g*8];
    }
    short8 bf[4];
    #pragma unroll
    for (int ci = 0; ci < 4; ci++) {
      int ct = (ci < 2) ? (wv*2 + ci) : (8 + wv*2 + (ci-2));
      bf[ci] = *(const short8*)&W2[(((size_t)ct*4 + kc)*64 + l)*8];
    }
    #pragma unroll
    for (int rt = 0; rt < 4; rt++)
      #pragma unroll
      for (int ci = 0; ci < 4; ci++)
        acc2[rt][ci] = __builtin_amdgcn_mfma_f32_16x16x32_bf16(af[rt], bf[ci], acc2[rt][ci], 0, 0, 0);
  }
  __syncthreads();
  #pragma unroll
  for (int ci = 0; ci < 2; ci++) {
    int ch = wv*32 + ci*16 + (l & 15);
    float f2 = fc2_b[ch], gb = gate_b[ch], sb = skip_b[ch];
    #pragma unroll
    for (int rt = 0; rt < 4; rt++)
      #pragma unroll
      for (int r = 0; r < 4; r++) {
        int row = rt*16 + (l >> 4)*4 + r;
        float hv = acc2[rt][ci][r] + f2;
        float gv = sigm(acc2[rt][ci+2][r] + gb);
        float sv = acc1[rt][ci+2][r] + sb;
        vbuf[row*129 + ch] = sv + hv*gv;
      }
  }
  __syncthreads();
  { int tk = tid >> 2, q = tid & 3;
    float s1 = 0.f, s2 = 0.f;
    #pragma unroll
    for (int i = 0; i < 32; i++) { float z = vbuf[tk*129 + q*32 + i]; s1 += z; s2 += z*z; }
    red[tk][q][0] = s1; red[tk][q][1] = s2;
  }
  __syncthreads();
  if ((tid & 3) == 0) {
    int tk = tid >> 2;
    float a = 0.f, b2 = 0.f;
    for (int p = 0; p < 4; p++) { a += red[tk][p][0]; b2 += red[tk][p][1]; }
    float mean = a * 0.0078125f;
    float var = b2 * 0.0078125f - mean*mean;
    mr[tk][0] = mean; mr[tk][1] = rsqrtf(fmaxf(var, 0.f) + 1e-5f);
  }
  __syncthreads();
  { int i = tid & 127;
    float lg = ln_g[i], lb = ln_b[i];
    for (int it = 0; it < 32; it++) {
      int tk = (tid >> 7) + it*2;
      float z = (vbuf[tk*129 + i] - mr[tk][0]) * mr[tk][1] * lg + lb;
      selb[(size_t)(n0+tk)*128 + i] = f2bu(z);
    }
  }
}

// ---------------- generic bf16 MFMA GEMM ------------------------------------
// outmode 0: fp32 row-major; 1: f16 row-major; 2: f16 permuted into the
// k_lscan_mfma C-fragment order: dst[((b/16*Tt + t)*32 + tile)*256 + lane*4 + r]
// where token row = b*Tt + t, tile = col/16, lane = (col&15)|(((b&15)>>2)<<4),
// r = b&3.
__global__ __launch_bounds__(256) void k_mm(
    const unsigned short* __restrict__ A, const unsigned short* __restrict__ Wp,
    const float* __restrict__ b0, const float* __restrict__ b1,
    void* __restrict__ out, int out_ld, int outmode, int Tt)
{
  const int r0 = blockIdx.x * 64;
  const int cb = blockIdx.y * 128;
  const int tid = threadIdx.x;
  const int wv = tid >> 6, l = tid & 63;
  __shared__ __align__(16) unsigned short As[64*136];
  #pragma unroll
  for (int i = 0; i < 4; i++) {
    int gi = i*256 + tid;
    int row = gi >> 4, g = gi & 15;
    uint4 v = *(const uint4*)(A + (size_t)(r0+row)*128 + g*8);
    *(uint4*)&As[row*136 + g*8] = v;
  }
  __syncthreads();
  f32x4 acc[4][2];
  #pragma unroll
  for (int rt = 0; rt < 4; rt++)
    #pragma unroll
    for (int ci = 0; ci < 2; ci++) acc[rt][ci] = (f32x4)(0.f);
  #pragma unroll
  for (int kc = 0; kc < 4; kc++) {
    short8 af[4];
    #pragma unroll
    for (int rt = 0; rt < 4; rt++) {
      int row = rt*16 + (l & 15), g = kc*4 + (l >> 4);
      af[rt] = *(const short8*)&As[row*136 + g*8];
    }
    short8 bf[2];
    #pragma unroll
    for (int ci = 0; ci < 2; ci++) {
      int ct = (cb >> 4) + wv*2 + ci;
      bf[ci] = *(const short8*)&Wp[(((size_t)ct*4 + kc)*64 + l)*8];
    }
    #pragma unroll
    for (int rt = 0; rt < 4; rt++)
      #pragma unroll
      for (int ci = 0; ci < 2; ci++)
        acc[rt][ci] = __builtin_amdgcn_mfma_f32_16x16x32_bf16(af[rt], bf[ci], acc[rt][ci], 0, 0, 0);
  }
  #pragma unroll
  for (int ci = 0; ci < 2; ci++) {
    int cl = cb + wv*32 + ci*16 + (l & 15);
    float bias = b0[cl] + (b1 ? b1[cl] : 0.f);
    #pragma unroll
    for (int rt = 0; rt < 4; rt++)
      #pragma unroll
      for (int r = 0; r < 4; r++) {
        int row = r0 + rt*16 + (l >> 4)*4 + r;
        float v = acc[rt][ci][r] + bias;
        if (outmode == 0) ((float*)out)[(size_t)row*out_ld + cl] = v;
        else if (outmode == 1) ((unsigned short*)out)[(size_t)row*out_ld + cl] = f2h(v);
        else {
          int bb = row / Tt, tt = row - bb*Tt;
          int tile = cl >> 4;
          int l2 = (cl & 15) | (((bb >> 2) & 3) << 4);
          int r2 = bb & 3;
          ((unsigned short*)out)[((((size_t)(bb >> 4)*Tt + tt)*32 + tile)*64 + l2)*4 + r2] = f2h(v);
        }
      }
  }
}

// ---------------- LSTM scan on the matrix pipe ------------------------------
// 16 batch elements per block, 16 blocks, 256 threads (4 waves). Per step the
// matvec is a [16x128]@[128x512] MFMA GEMM (32 mfma/wave). whh B-frags live
// in 128 VGPRs (4-wave block -> 256-VGPR budget). Wave wv owns col-tiles
// {g*8 + wv + gr*4} so all 4 gates of a channel group land in-register.
// h round-trips via double-buffered LDS A-tile: ONE barrier per step.
// pre arrives pre-permuted in C-frag order (k_mm outmode 2), f16, decoded
// scalar. hA stores h as BF16 (r14 bug: f2h stored f16 bits that the bf16
// MFMA misread as ~2^-15 garbage -> recurrence zeroed -> absmax 0.158).
__global__ __launch_bounds__(256, 1) void k_lscan_mfma(
    const unsigned short* __restrict__ prep,  // f16 [blk][Tt][32][64][4]
    const unsigned short* __restrict__ Wp,    // whh B-frags [32][4][64][8]
    const float* __restrict__ h0i, const float* __restrict__ c0i,
    int T, int Tt,                            // Tt = T, or 1 (constant input)
    unsigned short* __restrict__ ys,          // bf16 [b][T][128]
    float* __restrict__ hT, float* __restrict__ cT,
    unsigned short* __restrict__ hTb)         // bf16 [b][128]
{
  const int blk = blockIdx.x, tid = threadIdx.x;
  const int wv = tid >> 6, l = tid & 63;
  const int b0 = blk * 16;
  const int q = l >> 4, cl = l & 15;
  short8 bfr[4][2][4];   // [gate][grp][kc]
  #pragma unroll
  for (int g = 0; g < 4; g++)
    #pragma unroll
    for (int gr = 0; gr < 2; gr++) {
      int ct = g*8 + wv + gr*4;
      #pragma unroll
      for (int kc = 0; kc < 4; kc++)
        bfr[g][gr][kc] = *(const short8*)&Wp[(((size_t)ct*4 + kc)*64 + l)*8];
    }
  __shared__ __align__(16) unsigned short hA[2][16*136];
  #pragma unroll
  for (int i = 0; i < 8; i++) {
    int e = i*256 + tid;
    int m = e >> 7, k = e & 127;
    float h = h0i ? h0i[(size_t)(b0+m)*128 + k] : 0.f;
    hA[0][m*136 + k] = f2bu(h);          // bf16 (MFMA A input)
  }
  float cst[2][4];
  #pragma unroll
  for (int gr = 0; gr < 2; gr++) {
    int ch = (wv + gr*4)*16 + cl;
    #pragma unroll
    for (int r = 0; r < 4; r++) {
      int m = q*4 + r;
      cst[gr][r] = c0i ? c0i[(size_t)(b0+m)*128 + ch] : 0.f;
    }
  }
  __syncthreads();
  int cur = 0;
  for (int t = 0; t < T; t++) {
    // pre loads (coalesced uint2 per owned tile), consumed after the MFMA
    unsigned int pu[4][2][2];
    {
      int tu = (Tt == 1) ? 0 : t;
      const unsigned short* pb = prep + ((size_t)blk*Tt + tu)*8192;
      #pragma unroll
      for (int g = 0; g < 4; g++)
        #pragma unroll
        for (int gr = 0; gr < 2; gr++) {
          int tile = g*8 + wv + gr*4;
          const unsigned short* pp = pb + ((size_t)tile*64 + l)*4;
          pu[g][gr][0] = *(const unsigned int*)pp;
          pu[g][gr][1] = *(const unsigned int*)(pp + 2);
        }
    }
    short8 af[4];
    #pragma unroll
    for (int kc = 0; kc < 4; kc++)
      af[kc] = *(const short8*)&hA[cur][cl*136 + (kc*4 + q)*8];
    f32x4 acc[4][2];
    #pragma unroll
    for (int g = 0; g < 4; g++)
      #pragma unroll
      for (int gr = 0; gr < 2; gr++) {
        f32x4 a = (f32x4)(0.f);
        #pragma unroll
        for (int kc = 0; kc < 4; kc++)
          a = __builtin_amdgcn_mfma_f32_16x16x32_bf16(af[kc], bfr[g][gr][kc], a, 0, 0, 0);
        acc[g][gr] = a;
      }
    int nxt = cur ^ 1;
    #pragma unroll
    for (int gr = 0; gr < 2; gr++) {
      int ch = (wv + gr*4)*16 + cl;
      #pragma unroll
      for (int r = 0; r < 4; r++) {
        unsigned int ui = pu[0][gr][r >> 1], uf = pu[1][gr][r >> 1];
        unsigned int ug = pu[2][gr][r >> 1], uo = pu[3][gr][r >> 1];
        float pi = h2f((unsigned short)((r & 1) ? (ui >> 16) : (ui & 0xffff)));
        float pf = h2f((unsigned short)((r & 1) ? (uf >> 16) : (uf & 0xffff)));
        float pg = h2f((unsigned short)((r & 1) ? (ug >> 16) : (ug & 0xffff)));
        float po = h2f((unsigned short)((r & 1) ? (uo >> 16) : (uo & 0xffff)));
        float gi = sigm (acc[0][gr][r] + pi);
        float gf = sigm (acc[1][gr][r] + pf);
        float gg = tanhx(acc[2][gr][r] + pg);
        float go = sigm (acc[3][gr][r] + po);
        float c2 = gf*cst[gr][r] + gi*gg;
        cst[gr][r] = c2;
        float h = go * tanhx(c2);
        int m = q*4 + r;
        unsigned short hb = f2bu(h);
        hA[nxt][m*136 + ch] = hb;        // bf16 (MFMA A input)
        ys[((size_t)(b0+m)*T + t)*128 + ch] = hb;
        if (t == T-1) {
          hT[(size_t)(b0+m)*128 + ch] = h;
          cT[(size_t)(b0+m)*128 + ch] = c2;
          hTb[(size_t)(b0+m)*128 + ch] = hb;
        }
      }
    }
    __syncthreads();
    cur = nxt;
  }
}

// ---------------- cross attention: one block per (batch, head) -------------
__global__ __launch_bounds__(256) void k_attn(
    const float* __restrict__ Q, const float* __restrict__ K, const float* __restrict__ V,
    unsigned short* __restrict__ o)
{
  const int b = blockIdx.x, h = blockIdx.y, tid = threadIdx.x;
  __shared__ float Ks[168][33];
  __shared__ float Vs[168][32];
  __shared__ float Qs[24][32];
  __shared__ float Sc[24][169];
  __shared__ float red[24][8];
  __shared__ float rowm[24], rows[24];
  for (int e = tid; e < 168*32; e += 256) {
    int t = e >> 5, d = e & 31;
    Ks[t][d] = K[((size_t)b*168 + t)*128 + h*32 + d];
    Vs[t][d] = V[((size_t)b*168 + t)*128 + h*32 + d];
  }
  for (int e = tid; e < 24*32; e += 256) {
    int q = e >> 5, d = e & 31;
    Qs[q][d] = Q[((size_t)b*24 + q)*128 + h*32 + d];
  }
  __syncthreads();
  for (int e = tid; e < 24*168; e += 256) {
    int q = e / 168, t = e - q*168;
    float s = 0.f;
    #pragma unroll
    for (int d = 0; d < 32; d++) s += Qs[q][d]*Ks[t][d];
    Sc[q][t] = s * 0.17677669529663687f;
  }
  __syncthreads();
  int q = tid >> 3, l8 = tid & 7;
  if (q < 24) {
    float m = -1e30f;
    for (int t = l8; t < 168; t += 8) m = fmaxf(m, Sc[q][t]);
    red[q][l8] = m;
  }
  __syncthreads();
  if (q < 24 && l8 == 0) {
    float m = red[q][0];
    for (int p = 1; p < 8; p++) m = fmaxf(m, red[q][p]);
    rowm[q] = m;
  }
  __syncthreads();
  if (q < 24) {
    float s = 0.f;
    for (int t = l8; t < 168; t += 8) {
      float e2 = __expf(Sc[q][t] - rowm[q]);
      Sc[q][t] = e2; s += e2;
    }
    red[q][l8] = s;
  }
  __syncthreads();
  if (q < 24 && l8 == 0) {
    float s = 0.f;
    for (int p = 0; p < 8; p++) s += red[q][p];
    rows[q] = 1.f/s;
  }
  __syncthreads();
  for (int e = tid; e < 24*32; e += 256) {
    int qq = e >> 5, d = e & 31;
    float acc = 0.f;
    for (int t = 0; t < 168; t++) acc += Sc[qq][t]*Vs[t][d];
    o[((size_t)b*24 + qq)*128 + h*32 + d] = f2bu(acc * rows[qq]);
  }
}

// ---------------- post-attention GRN (MFMA, identity skip) -----------------
__global__ __launch_bounds__(256) void k_pa_mfma(
    const float* __restrict__ xin, const unsigned short* __restrict__ pk,
    const float* __restrict__ fc1_b, const float* __restrict__ fc2_b,
    const float* __restrict__ gate_b, const float* __restrict__ ln_g,
    const float* __restrict__ ln_b, float* __restrict__ out)
{
  const int n0 = blockIdx.x * 64;
  const int tid = threadIdx.x;
  const int wv = tid >> 6, l = tid & 63;
  __shared__ __align__(16) unsigned short As[64*136];
  __shared__ __align__(16) unsigned short A2s[64*136];
  __shared__ float xs[64*129];
  __shared__ float red[64][4][2];
  __shared__ float mr[64][2];
  for (int i2 = 0; i2 < 8; i2++) {
    int t4 = i2*256 + tid;
    int r = t4 >> 5, cc = (t4 & 31) << 2;
    float4 v = *(const float4*)(xin + (size_t)(n0 + r)*128 + cc);
    xs[r*129 + cc] = v.x; xs[r*129 + cc+1] = v.y;
    xs[r*129 + cc+2] = v.z; xs[r*129 + cc+3] = v.w;
    As[r*136 + cc] = f2bu(v.x); As[r*136 + cc+1] = f2bu(v.y);
    As[r*136 + cc+2] = f2bu(v.z); As[r*136 + cc+3] = f2bu(v.w);
  }
  __syncthreads();
  const unsigned short* W1 = pk + PK_PAF1;
  f32x4 acc1[4][2];
  #pragma unroll
  for (int rt = 0; rt < 4; rt++)
    #pragma unroll
    for (int ci = 0; ci < 2; ci++) acc1[rt][ci] = (f32x4)(0.f);
  #pragma unroll
  for (int kc = 0; kc < 4; kc++) {
    short8 af[4];
    #pragma unroll
    for (int rt = 0; rt < 4; rt++) {
      int row = rt*16 + (l & 15), g = kc*4 + (l >> 4);
      af[rt] = *(const short8*)&As[row*136 + g*8];
    }
    short8 bf[2];
    #pragma unroll
    for (int ci = 0; ci < 2; ci++) {
      int ct = wv*2 + ci;
      bf[ci] = *(const short8*)&W1[(((size_t)ct*4 + kc)*64 + l)*8];
    }
    #pragma unroll
    for (int rt = 0; rt < 4; rt++)
      #pragma unroll
      for (int ci = 0; ci < 2; ci++)
        acc1[rt][ci] = __builtin_amdgcn_mfma_f32_16x16x32_bf16(af[rt], bf[ci], acc1[rt][ci], 0, 0, 0);
  }
  __syncthreads();
  #pragma unroll
  for (int ci = 0; ci < 2; ci++) {
    int ch = wv*32 + ci*16 + (l & 15);
    float fb = fc1_b[ch];
    #pragma unroll
    for (int rt = 0; rt < 4; rt++)
      #pragma unroll
      for (int r = 0; r < 4; r++) {
        int row = rt*16 + (l >> 4)*4 + r;
        A2s[row*136 + ch] = f2bu(eluf(acc1[rt][ci][r] + fb));
      }
  }
  __syncthreads();
  const unsigned short* W2 = pk + PK_PAF2G;
  f32x4 acc2[4][4];
  #pragma unroll
  for (int rt = 0; rt < 4; rt++)
    #pragma unroll
    for (int ci = 0; ci < 4; ci++) acc2[rt][ci] = (f32x4)(0.f);
  #pragma unroll
  for (int kc = 0; kc < 4; kc++) {
    short8 af[4];
    #pragma unroll
    for (int rt = 0; rt < 4; rt++) {
      int row = rt*16 + (l & 15), g = kc*4 + (l >> 4);
      af[rt] = *(const short8*)&A2s[row*136 + g*8];
    }
    short8 bf[4];
    #pragma unroll
    for (int ci = 0; ci < 4; ci++) {
      int ct = (ci < 2) ? (wv*2 + ci) : (8 + wv*2 + (ci-2));
      bf[ci] = *(const short8*)&W2[(((size_t)ct*4 + kc)*64 + l)*8];
    }
    #pragma unroll
    for (int rt = 0; rt < 4; rt++)
      #pragma unroll
      for (int ci = 0; ci < 4; ci++)
        acc2[rt][ci] = __builtin_amdgcn_mfma_f32_16x16x32_bf16(af[rt], bf[ci], acc2[rt][ci], 0, 0, 0);
  }
  __syncthreads();
  #pragma unroll
  for (int ci = 0; ci < 2; ci++) {
    int ch = wv*32 + ci*16 + (l & 15);
    float f2 = fc2_b[ch], gb = gate_b[ch];
    #pragma unroll
    for (int rt = 0; rt < 4; rt++)
      #pragma unroll
      for (int r = 0; r < 4; r++) {
        int row = rt*16 + (l >> 4)*4 + r;
        float hv = acc2[rt][ci][r] + f2;
        float gv = sigm(acc2[rt][ci+2][r] + gb);
        xs[row*129 + ch] = xs[row*129 + ch] + hv*gv;
      }
  }
  __syncthreads();
  { int tk = tid >> 2, q = tid & 3;
    float s1 = 0.f, s2 = 0.f;
    #pragma unroll
    for (int i = 0; i < 32; i++) { float z = xs[tk*129 + q*32 + i]; s1 += z; s2 += z*z; }
    red[tk][q][0] = s1; red[tk][q][1] = s2;
  }
  __syncthreads();
  if ((tid & 3) == 0) {
    int tk = tid >> 2;
    float a = 0.f, b2 = 0.f;
    for (int p = 0; p < 4; p++) { a += red[tk][p][0]; b2 += red[tk][p][1]; }
    float mean = a * 0.0078125f;
    float var = b2 * 0.0078125f - mean*mean;
    mr[tk][0] = mean; mr[tk][1] = rsqrtf(fmaxf(var, 0.f) + 1e-5f);
  }
  __syncthreads();
  { int i = tid & 127;
    float lg = ln_g[i], lb = ln_b[i];
    for (int it = 0; it < 32; it++) {
      int tk = (tid >> 7) + it*2;
      out[(size_t)(n0+tk)*128 + i] = (xs[tk*129 + i] - mr[tk][0]) * mr[tk][1] * lg + lb;
    }
  }
}

// ---------------- final projection 128 -> 6 --------------------------------
__global__ __launch_bounds__(256) void k_final(
    const float* __restrict__ a, const float* __restrict__ fo_w,
    const float* __restrict__ fo_b, float* __restrict__ out)
{
  int idx = blockIdx.x*256 + threadIdx.x;
  if (idx >= NDTOK*6) return;
  int n = idx / 6, j = idx - n*6;
  const float* ar = a + (size_t)n*128;
  const float* w = fo_w + j*128;
  float s = fo_b[j];
  #pragma unroll 4
  for (int d = 0; d < 128; d++) s += ar[d]*w[d];
  out[idx] = s;
}

extern "C" void kernel_launch(void* const* d_in, const int* in_sizes, int n_in,
                              void* d_out, int out_size, void* d_ws, size_t ws_size,
                              hipStream_t stream) {
  (void)in_sizes; (void)n_in; (void)out_size; (void)ws_size;
  const float* x      = (const float*)d_in[0];
  const float* vfc1w  = (const float*)d_in[1];
  const float* vfc1b  = (const float*)d_in[2];
  const float* vfc2w  = (const float*)d_in[3];
  const float* vfc2b  = (const float*)d_in[4];
  const float* vgw    = (const float*)d_in[5];
  const float* vgb    = (const float*)d_in[6];
  const float* vskw   = (const float*)d_in[7];
  const float* vskb   = (const float*)d_in[8];
  const float* vlng   = (const float*)d_in[9];
  const float* vlnb   = (const float*)d_in[10];
  const float* gfc1w  = (const float*)d_in[11];
  const float* gfc1b  = (const float*)d_in[12];
  const float* gfc2w  = (const float*)d_in[13];
  const float* gfc2b  = (const float*)d_in[14];
  const float* ggw    = (const float*)d_in[15];
  const float* ggb    = (const float*)d_in[16];
  const float* gskw   = (const float*)d_in[17];
  const float* gskb   = (const float*)d_in[18];
  const float* glng   = (const float*)d_in[19];
  const float* glnb   = (const float*)d_in[20];
  const float* encwih = (const float*)d_in[21];
  const float* encwhh = (const float*)d_in[22];
  const float* encbih = (const float*)d_in[23];
  const float* encbhh = (const float*)d_in[24];
  const float* decwih = (const float*)d_in[25];
  const float* decwhh = (const float*)d_in[26];
  const float* decbih = (const float*)d_in[27];
  const float* decbhh = (const float*)d_in[28];
  const float* ainw   = (const float*)d_in[29];
  const float* ainb   = (const float*)d_in[30];
  const float* aoutw  = (const float*)d_in[31];
  const float* aoutb  = (const float*)d_in[32];
  const float* pfc1w  = (const float*)d_in[33];
  const float* pfc1b  = (const float*)d_in[34];
  const float* pfc2w  = (const float*)d_in[35];
  const float* pfc2b  = (const float*)d_in[36];
  const float* pgw    = (const float*)d_in[37];
  const float* pgb    = (const float*)d_in[38];
  const float* plng   = (const float*)d_in[39];
  const float* plnb   = (const float*)d_in[40];
  const float* fow    = (const float*)d_in[41];
  const float* fob    = (const float*)d_in[42];

  float* ws = (float*)d_ws;
  // ---- workspace (float offsets). pk = 630,784 fl. proc2 = 24,772,608 fl.
  // prep (enc pre, permuted f16 [16][168][8192]us) = 11,010,048 fl, aliases
  // the dead proc2 region. Kb aliases dead prep. hT/cT are [256][128] f32 =
  // 32,768 fl each -> 40,000 spacing (r13 NaN: 10,000 spacing overlapped).
  unsigned short* pk = (unsigned short*)ws;                 // [0, 630,784)
  unsigned short* proc2 = (unsigned short*)(ws + 650000);   // [650,000, 25,422,608)
  unsigned short* prep  = (unsigned short*)(ws + 650000);   // alias (proc2 dead)
  float* Kb   = ws + 650000;                                // alias (prep dead) -> 6,155,024
  float* Vb   = ws + 6200000;                               // -> 11,705,024
  unsigned short* pre2p = (unsigned short*)(ws + 12000000); // [16][24][8192]us -> 13,572,864
  unsigned short* pd0p  = (unsigned short*)(ws + 13600000); // [16][1][8192]us -> 13,665,536
  float* Qb   = ws + 13700000;                              // -> 14,486,432
  unsigned short* attb = (unsigned short*)(ws + 14500000);  // -> 14,696,608
  float* ato  = ws + 14800000;                              // -> 15,586,432
  float* pao  = ws + 15700000;                              // -> 16,486,432
  unsigned short* selb  = (unsigned short*)(ws + 25450000); // -> 28,202,512
  unsigned short* encob = (unsigned short*)(ws + 28250000); // -> 31,002,512
  unsigned short* ys0b  = (unsigned short*)(ws + 31050000); // -> 33,802,512
  unsigned short* dys0b = (unsigned short*)(ws + 33850000); // -> 34,046,608
  unsigned short* dout2b = (unsigned short*)(ws + 34050000);// -> 34,246,608
  float* hT0  = ws + 34250000;  float* cT0 = ws + 34290000; // each 32,768 fl
  float* hT1  = ws + 34330000;  float* cT1 = ws + 34370000;
  unsigned short* hT1b = (unsigned short*)(ws + 34410000);  // 16,384 fl
  float* dscr = ws + 34450000;  // dummy hT/cT/hTb slices (uses +0..192,768)

  // 1. pack bf16 MFMA fragments (incl. whh for the MFMA scans)
  k_pack<<<dim3(128, 9), dim3(256), 0, stream>>>(vfc2w, vgw, pk + PK_VSN, 128, 256, 128, 16384, 16384, 32768);
  k_pack<<<dim3(1152), dim3(256), 0, stream>>>(gfc1w, gskw, pk + PK_GC1, 1152, 256, 128, 0, 0, 0);
  k_pack<<<dim3(128), dim3(256), 0, stream>>>(gfc2w, ggw, pk + PK_GC2, 128, 256, 128, 0, 0, 0);
  k_pack<<<dim3(256), dim3(256), 0, stream>>>(encwih, encwih, pk + PK_ENC0, 128, 512, 512, 0, 0, 0);
  k_pack<<<dim3(256), dim3(256), 0, stream>>>(encwih + 65536, encwih, pk + PK_ENC1, 128, 512, 512, 0, 0, 0);
  k_pack<<<dim3(256), dim3(256), 0, stream>>>(decwih, decwih, pk + PK_DEC0, 128, 512, 512, 0, 0, 0);
  k_pack<<<dim3(256), dim3(256), 0, stream>>>(decwih + 65536, decwih, pk + PK_DEC1, 128, 512, 512, 0, 0, 0);
  k_pack<<<dim3(192), dim3(256), 0, stream>>>(ainw, ainw, pk + PK_AIN, 128, 384, 384, 0, 0, 0);
  k_pack<<<dim3(64), dim3(256), 0, stream>>>(aoutw, aoutw, pk + PK_AOUT, 128, 128, 128, 0, 0, 0);
  k_pack<<<dim3(64), dim3(256), 0, stream>>>(pfc1w, pfc1w, pk + PK_PAF1, 128, 128, 128, 0, 0, 0);
  k_pack<<<dim3(128), dim3(256), 0, stream>>>(pfc2w, pgw, pk + PK_PAF2G, 128, 256, 128, 0, 0, 0);
  k_pack<<<dim3(256), dim3(256), 0, stream>>>(encwhh, encwhh, pk + PK_WHH_E0, 128, 512, 512, 0, 0, 0);
  k_pack<<<dim3(256), dim3(256), 0, stream>>>(encwhh + 65536, encwhh, pk + PK_WHH_E1, 128, 512, 512, 0, 0, 0);
  k_pack<<<dim3(256), dim3(256), 0, stream>>>(decwhh, decwhh, pk + PK_WHH_D0, 128, 512, 512, 0, 0, 0);
  k_pack<<<dim3(256), dim3(256), 0, stream>>>(decwhh + 65536, decwhh, pk + PK_WHH_D1, 128, 512, 512, 0, 0, 0);
  // 2. VSN per-feature GRNs (MFMA)
  k_vsn_mfma<<<dim3(672, 9), dim3(256), 0, stream>>>(x, vfc1w, vfc1b, pk,
      vfc2b, vgb, vskw, vskb, vlng, vlnb, proc2);
  // 3. grand-selection GRN (MFMA, fused)
  k_gc_mfma<<<dim3(672), dim3(256), 0, stream>>>(proc2, pk, gfc1b, gfc2b, ggb,
      gskb, glng, glnb, selb);
  // 4. encoder layer 0: input projection (permuted f16) + MFMA scan
  k_mm<<<dim3(672, 4), dim3(256), 0, stream>>>(selb, pk + PK_ENC0, encbih, encbhh, prep, 512, 2, TSE);
  k_lscan_mfma<<<dim3(16), dim3(256), 0, stream>>>(prep, pk + PK_WHH_E0, nullptr, nullptr,
      TSE, TSE, ys0b, hT0, cT0, (unsigned short*)dscr);
  // 5. encoder layer 1
  k_mm<<<dim3(672, 4), dim3(256), 0, stream>>>(ys0b, pk + PK_ENC1, encbih + 512, encbhh + 512, prep, 512, 2, TSE);
  k_lscan_mfma<<<dim3(16), dim3(256), 0, stream>>>(prep, pk + PK_WHH_E1, nullptr, nullptr,
      TSE, TSE, encob, hT1, cT1, hT1b);
  // 6. decoder layer 0 (constant input hT1)
  k_mm<<<dim3(4, 4), dim3(256), 0, stream>>>(hT1b, pk + PK_DEC0, decbih, decbhh, pd0p, 512, 2, 1);
  k_lscan_mfma<<<dim3(16), dim3(256), 0, stream>>>(pd0p, pk + PK_WHH_D0, hT0, cT0,
      TSD, 1, dys0b, dscr + 40000, dscr + 80000, (unsigned short*)dscr);
  // 7. decoder layer 1
  k_mm<<<dim3(96, 4), dim3(256), 0, stream>>>(dys0b, pk + PK_DEC1, decbih + 512, decbhh + 512, pre2p, 512, 2, TSD);
  k_lscan_mfma<<<dim3(16), dim3(256), 0, stream>>>(pre2p, pk + PK_WHH_D1, hT1, cT1,
      TSD, TSD, dout2b, dscr + 120000, dscr + 160000, (unsigned short*)dscr);
  // 8. attention projections
  k_mm<<<dim3(96, 1), dim3(256), 0, stream>>>(dout2b, pk + PK_AIN, ainb, nullptr, Qb, 128, 0, 0);
  k_mm<<<dim3(672, 1), dim3(256), 0, stream>>>(encob, pk + PK_AIN + 16384, ainb + 128, nullptr, Kb, 128, 0, 0);
  k_mm<<<dim3(672, 1), dim3(256), 0, stream>>>(encob, pk + PK_AIN + 32768, ainb + 256, nullptr, Vb, 128, 0, 0);
  // 9. attention core
  k_attn<<<dim3(256, 4), dim3(256), 0, stream>>>(Qb, Kb, Vb, attb);
  // 10. attention output projection
  k_mm<<<dim3(96, 1), dim3(256), 0, stream>>>(attb, pk + PK_AOUT, aoutb, nullptr, ato, 128, 0, 0);
  // 11. post-attention GRN (MFMA)
  k_pa_mfma<<<dim3(96), dim3(256), 0, stream>>>(ato, pk, pfc1b, pfc2b, pgb,
      plng, plnb, pao);
  // 12. final projection
  k_final<<<dim3(144), dim3(256), 0, stream>>>(pao, fow, fob, (float*)d_out);
}

// Round 16
// 740.063 us; speedup vs baseline: 1.8694x; 1.8694x over previous
//
#include <hip/hip_runtime.h>
#include <hip/hip_bf16.h>

#define NBATCH 256
#define TSE 168
#define TSD 24
#define NTOK (NBATCH*TSE)   // 43008
#define NDTOK (NBATCH*TSD)  // 6144

// packed bf16 MFMA-B-fragment offsets (ushort units, region base pk)
#define PK_VSN    0         // 9 x [K=128, NC=256]  = 294912
#define PK_GC1    294912    // [K=1152, NC=256]     = 294912
#define PK_GC2    589824    // [K=128, NC=256]      = 32768
#define PK_ENC0   622592    // [128,512]            = 65536
#define PK_ENC1   688128    // [128,512]            = 65536
#define PK_DEC0   753664    // [128,512]            = 65536
#define PK_DEC1   819200    // [128,512]            = 65536
#define PK_AIN    884736    // [128,384]            = 49152
#define PK_AOUT   933888    // [128,128]            = 16384
#define PK_PAF1   950272    // [128,128]            = 16384
#define PK_PAF2G  966656    // [128,256]            = 32768
// pk total = 999,424 ushorts = 499,712 floats

typedef __attribute__((ext_vector_type(8))) short short8;
typedef __attribute__((ext_vector_type(4))) float f32x4;
typedef __attribute__((ext_vector_type(2))) __fp16 fp16x2;

__device__ __forceinline__ float sigm(float x){ return 1.f/(1.f + __expf(-x)); }
__device__ __forceinline__ float tanhx(float x){
  float cx = fminf(fmaxf(x, -15.f), 15.f);
  float e = __expf(2.f*cx);
  return (e-1.f)/(e+1.f);
}
__device__ __forceinline__ float eluf(float x){ return x > 0.f ? x : (__expf(x)-1.f); }
__device__ __forceinline__ unsigned short f2bu(float v){
  unsigned int u = __float_as_uint(v);
  u = (u + 0x7fffu + ((u>>16)&1u)) >> 16;
  return (unsigned short)u;
}
__device__ __forceinline__ unsigned int pkh(float a, float b){
  union { fp16x2 h; unsigned int u; } v;
  v.h = __builtin_amdgcn_cvt_pkrtz(a, b);
  return v.u;
}
__device__ __forceinline__ unsigned short f2h(float x){
  union { _Float16 h; unsigned short u; } v;
  v.h = (_Float16)x; return v.u;
}
__device__ __forceinline__ float h2f(unsigned short u){
  union { unsigned short u; _Float16 h; } v;
  v.u = u; return (float)v.h;
}
__device__ __forceinline__ float fd2(unsigned int a, unsigned int b, float c){
  union { unsigned int u; fp16x2 h; } ua, ub;
  ua.u = a; ub.u = b;
  return __builtin_amdgcn_fdot2(ua.h, ub.h, c, false);
}

// ---------------- pack weights into bf16 MFMA B-fragment order -------------
// dst layout: [ct][kc][lane(64)][j(8)], ct=n/16, kc=k/32, lane=(n%16)+16*((k%32)/8), j=k%8
__global__ __launch_bounds__(256) void k_pack(
    const float* __restrict__ s0, const float* __restrict__ s1,
    unsigned short* __restrict__ dst, int K, int NC, int nsplit,
    int s0bs, int s1bs, int dstbs)
{
  int id = blockIdx.x*256 + threadIdx.x;
  if (id >= K*NC) return;
  int by = blockIdx.y;
  int n = id / K, k = id - n*K;
  float v = (n < nsplit) ? s0[(size_t)by*s0bs + (size_t)n*K + k]
                         : s1[(size_t)by*s1bs + (size_t)(n-nsplit)*K + k];
  int ct = n >> 4, kc = k >> 5;
  int lane = (n & 15) | (((k >> 3) & 3) << 4);
  int j = k & 7;
  int KC = K >> 5;
  dst[(size_t)by*dstbs + (((size_t)ct*KC + kc)*64 + lane)*8 + j] = f2bu(v);
}

// ---------------- VSN per-feature GRN (MFMA) -> proc2 chunk-major bf16 -----
__global__ __launch_bounds__(256) void k_vsn_mfma(
    const float* __restrict__ x, const float* __restrict__ fc1_w, const float* __restrict__ fc1_b,
    const unsigned short* __restrict__ pk, const float* __restrict__ fc2_b,
    const float* __restrict__ gate_b, const float* __restrict__ skip_w,
    const float* __restrict__ skip_b, const float* __restrict__ ln_g,
    const float* __restrict__ ln_b, unsigned short* __restrict__ proc2)
{
  const int f = blockIdx.y;
  const int nb = blockIdx.x;
  const int n0 = nb * 64;
  const int tid = threadIdx.x;
  const int wv = tid >> 6, l = tid & 63;
  __shared__ __align__(16) unsigned short As[64*136];
  __shared__ float xs[64];
  __shared__ float vbuf[64*129];
  __shared__ float red[64][4][2];
  __shared__ float mr[64][2];
  if (tid < 64) xs[tid] = x[(size_t)(n0+tid)*9 + f];
  __syncthreads();
  { int i = tid & 127;
    float w1 = fc1_w[f*128 + i], b1 = fc1_b[f*128 + i];
    for (int it = 0; it < 32; it++) {
      int tk = (tid >> 7) + it*2;
      As[tk*136 + i] = f2bu(eluf(xs[tk]*w1 + b1));
    }
  }
  __syncthreads();
  const unsigned short* Wp = pk + PK_VSN + (size_t)f*32768;
  f32x4 acc[4][4];
  #pragma unroll
  for (int rt = 0; rt < 4; rt++)
    #pragma unroll
    for (int ci = 0; ci < 4; ci++) acc[rt][ci] = (f32x4)(0.f);
  #pragma unroll
  for (int kc = 0; kc < 4; kc++) {
    short8 af[4];
    #pragma unroll
    for (int rt = 0; rt < 4; rt++) {
      int row = rt*16 + (l & 15), g = kc*4 + (l >> 4);
      af[rt] = *(const short8*)&As[row*136 + g*8];
    }
    short8 bf[4];
    #pragma unroll
    for (int ci = 0; ci < 4; ci++) {
      int ct = (ci < 2) ? (wv*2 + ci) : (8 + wv*2 + (ci-2));
      bf[ci] = *(const short8*)&Wp[(((size_t)ct*4 + kc)*64 + l)*8];
    }
    #pragma unroll
    for (int rt = 0; rt < 4; rt++)
      #pragma unroll
      for (int ci = 0; ci < 4; ci++)
        acc[rt][ci] = __builtin_amdgcn_mfma_f32_16x16x32_bf16(af[rt], bf[ci], acc[rt][ci], 0, 0, 0);
  }
  __syncthreads();
  #pragma unroll
  for (int ci = 0; ci < 2; ci++) {
    int ch = wv*32 + ci*16 + (l & 15);
    float fb = fc2_b[f*128 + ch], gb = gate_b[f*128 + ch];
    float sw = skip_w[f*128 + ch], sb = skip_b[f*128 + ch];
    #pragma unroll
    for (int rt = 0; rt < 4; rt++)
      #pragma unroll
      for (int r = 0; r < 4; r++) {
        int row = rt*16 + (l >> 4)*4 + r;
        float hv = acc[rt][ci][r] + fb;
        float gv = sigm(acc[rt][ci+2][r] + gb);
        float sv = xs[row]*sw + sb;
        vbuf[row*129 + ch] = sv + hv*gv;
      }
  }
  __syncthreads();
  { int tk = tid >> 2, q = tid & 3;
    float s1 = 0.f, s2 = 0.f;
    #pragma unroll
    for (int i = 0; i < 32; i++) { float z = vbuf[tk*129 + q*32 + i]; s1 += z; s2 += z*z; }
    red[tk][q][0] = s1; red[tk][q][1] = s2;
  }
  __syncthreads();
  if ((tid & 3) == 0) {
    int tk = tid >> 2;
    float a = 0.f, b2 = 0.f;
    for (int p = 0; p < 4; p++) { a += red[tk][p][0]; b2 += red[tk][p][1]; }
    float mean = a * 0.0078125f;
    float var = b2 * 0.0078125f - mean*mean;
    mr[tk][0] = mean; mr[tk][1] = rsqrtf(fmaxf(var, 0.f) + 1e-5f);
  }
  __syncthreads();
  { int i = tid & 127;
    float lg = ln_g[f*128 + i], lb = ln_b[f*128 + i];
    size_t base = ((size_t)nb*9 + f)*8192;
    for (int it = 0; it < 32; it++) {
      int tk = (tid >> 7) + it*2;
      float z = (vbuf[tk*129 + i] - mr[tk][0]) * mr[tk][1] * lg + lb;
      proc2[base + tk*128 + i] = f2bu(z);
    }
  }
}

// ---------------- grand-selection GRN (MFMA, fully fused) -> sel bf16 ------
__global__ __launch_bounds__(256) void k_gc_mfma(
    const unsigned short* __restrict__ proc2, const unsigned short* __restrict__ pk,
    const float* __restrict__ fc1_b, const float* __restrict__ fc2_b,
    const float* __restrict__ gate_b, const float* __restrict__ skip_b,
    const float* __restrict__ ln_g, const float* __restrict__ ln_b,
    unsigned short* __restrict__ selb)
{
  const int nb = blockIdx.x;
  const int n0 = nb * 64;
  const int tid = threadIdx.x;
  const int wv = tid >> 6, l = tid & 63;
  __shared__ __align__(16) unsigned short As[64*136];
  __shared__ __align__(16) unsigned short A2s[64*136];
  __shared__ float vbuf[64*129];
  __shared__ float red[64][4][2];
  __shared__ float mr[64][2];
  const unsigned short* W1 = pk + PK_GC1;
  f32x4 acc1[4][4];
  #pragma unroll
  for (int rt = 0; rt < 4; rt++)
    #pragma unroll
    for (int ci = 0; ci < 4; ci++) acc1[rt][ci] = (f32x4)(0.f);
  for (int c = 0; c < 9; c++) {
    size_t cbase = ((size_t)nb*9 + c)*8192;
    #pragma unroll
    for (int i = 0; i < 4; i++) {
      int gi = i*256 + tid;
      int row = gi >> 4, g = gi & 15;
      uint4 v = *(const uint4*)(proc2 + cbase + row*128 + g*8);
      *(uint4*)&As[row*136 + g*8] = v;
    }
    __syncthreads();
    #pragma unroll
    for (int kc = 0; kc < 4; kc++) {
      int kk = c*4 + kc;
      short8 af[4];
      #pragma unroll
      for (int rt = 0; rt < 4; rt++) {
        int row = rt*16 + (l & 15), g = kc*4 + (l >> 4);
        af[rt] = *(const short8*)&As[row*136 + g*8];
      }
      short8 bf[4];
      #pragma unroll
      for (int ci = 0; ci < 4; ci++) {
        int ct = (ci < 2) ? (wv*2 + ci) : (8 + wv*2 + (ci-2));
        bf[ci] = *(const short8*)&W1[(((size_t)ct*36 + kk)*64 + l)*8];
      }
      #pragma unroll
      for (int rt = 0; rt < 4; rt++)
        #pragma unroll
        for (int ci = 0; ci < 4; ci++)
          acc1[rt][ci] = __builtin_amdgcn_mfma_f32_16x16x32_bf16(af[rt], bf[ci], acc1[rt][ci], 0, 0, 0);
    }
    __syncthreads();
  }
  #pragma unroll
  for (int ci = 0; ci < 2; ci++) {
    int ch = wv*32 + ci*16 + (l & 15);
    float fb = fc1_b[ch];
    #pragma unroll
    for (int rt = 0; rt < 4; rt++)
      #pragma unroll
      for (int r = 0; r < 4; r++) {
        int row = rt*16 + (l >> 4)*4 + r;
        A2s[row*136 + ch] = f2bu(eluf(acc1[rt][ci][r] + fb));
      }
  }
  __syncthreads();
  const unsigned short* W2 = pk + PK_GC2;
  f32x4 acc2[4][4];
  #pragma unroll
  for (int rt = 0; rt < 4; rt++)
    #pragma unroll
    for (int ci = 0; ci < 4; ci++) acc2[rt][ci] = (f32x4)(0.f);
  #pragma unroll
  for (int kc = 0; kc < 4; kc++) {
    short8 af[4];
    #pragma unroll
    for (int rt = 0; rt < 4; rt++) {
      int row = rt*16 + (l & 15), g = kc*4 + (l >> 4);
      af[rt] = *(const short8*)&A2s[row*136 + g*8];
    }
    short8 bf[4];
    #pragma unroll
    for (int ci = 0; ci < 4; ci++) {
      int ct = (ci < 2) ? (wv*2 + ci) : (8 + wv*2 + (ci-2));
      bf[ci] = *(const short8*)&W2[(((size_t)ct*4 + kc)*64 + l)*8];
    }
    #pragma unroll
    for (int rt = 0; rt < 4; rt++)
      #pragma unroll
      for (int ci = 0; ci < 4; ci++)
        acc2[rt][ci] = __builtin_amdgcn_mfma_f32_16x16x32_bf16(af[rt], bf[ci], acc2[rt][ci], 0, 0, 0);
  }
  __syncthreads();
  #pragma unroll
  for (int ci = 0; ci < 2; ci++) {
    int ch = wv*32 + ci*16 + (l & 15);
    float f2 = fc2_b[ch], gb = gate_b[ch], sb = skip_b[ch];
    #pragma unroll
    for (int rt = 0; rt < 4; rt++)
      #pragma unroll
      for (int r = 0; r < 4; r++) {
        int row = rt*16 + (l >> 4)*4 + r;
        float hv = acc2[rt][ci][r] + f2;
        float gv = sigm(acc2[rt][ci+2][r] + gb);
        float sv = acc1[rt][ci+2][r] + sb;
        vbuf[row*129 + ch] = sv + hv*gv;
      }
  }
  __syncthreads();
  { int tk = tid >> 2, q = tid & 3;
    float s1 = 0.f, s2 = 0.f;
    #pragma unroll
    for (int i = 0; i < 32; i++) { float z = vbuf[tk*129 + q*32 + i]; s1 += z; s2 += z*z; }
    red[tk][q][0] = s1; red[tk][q][1] = s2;
  }
  __syncthreads();
  if ((tid & 3) == 0) {
    int tk = tid >> 2;
    float a = 0.f, b2 = 0.f;
    for (int p = 0; p < 4; p++) { a += red[tk][p][0]; b2 += red[tk][p][1]; }
    float mean = a * 0.0078125f;
    float var = b2 * 0.0078125f - mean*mean;
    mr[tk][0] = mean; mr[tk][1] = rsqrtf(fmaxf(var, 0.f) + 1e-5f);
  }
  __syncthreads();
  { int i = tid & 127;
    float lg = ln_g[i], lb = ln_b[i];
    for (int it = 0; it < 32; it++) {
      int tk = (tid >> 7) + it*2;
      float z = (vbuf[tk*129 + i] - mr[tk][0]) * mr[tk][1] * lg + lb;
      selb[(size_t)(n0+tk)*128 + i] = f2bu(z);
    }
  }
}

// ---------------- generic bf16 MFMA GEMM, out fp32 or f16 ------------------
__global__ __launch_bounds__(256) void k_mm(
    const unsigned short* __restrict__ A, const unsigned short* __restrict__ Wp,
    const float* __restrict__ b0, const float* __restrict__ b1,
    void* __restrict__ out, int out_ld, int outmode)
{
  const int r0 = blockIdx.x * 64;
  const int cb = blockIdx.y * 128;
  const int tid = threadIdx.x;
  const int wv = tid >> 6, l = tid & 63;
  __shared__ __align__(16) unsigned short As[64*136];
  #pragma unroll
  for (int i = 0; i < 4; i++) {
    int gi = i*256 + tid;
    int row = gi >> 4, g = gi & 15;
    uint4 v = *(const uint4*)(A + (size_t)(r0+row)*128 + g*8);
    *(uint4*)&As[row*136 + g*8] = v;
  }
  __syncthreads();
  f32x4 acc[4][2];
  #pragma unroll
  for (int rt = 0; rt < 4; rt++)
    #pragma unroll
    for (int ci = 0; ci < 2; ci++) acc[rt][ci] = (f32x4)(0.f);
  #pragma unroll
  for (int kc = 0; kc < 4; kc++) {
    short8 af[4];
    #pragma unroll
    for (int rt = 0; rt < 4; rt++) {
      int row = rt*16 + (l & 15), g = kc*4 + (l >> 4);
      af[rt] = *(const short8*)&As[row*136 + g*8];
    }
    short8 bf[2];
    #pragma unroll
    for (int ci = 0; ci < 2; ci++) {
      int ct = (cb >> 4) + wv*2 + ci;
      bf[ci] = *(const short8*)&Wp[(((size_t)ct*4 + kc)*64 + l)*8];
    }
    #pragma unroll
    for (int rt = 0; rt < 4; rt++)
      #pragma unroll
      for (int ci = 0; ci < 2; ci++)
        acc[rt][ci] = __builtin_amdgcn_mfma_f32_16x16x32_bf16(af[rt], bf[ci], acc[rt][ci], 0, 0, 0);
  }
  #pragma unroll
  for (int ci = 0; ci < 2; ci++) {
    int cl = cb + wv*32 + ci*16 + (l & 15);
    float bias = b0[cl] + (b1 ? b1[cl] : 0.f);
    #pragma unroll
    for (int rt = 0; rt < 4; rt++)
      #pragma unroll
      for (int r = 0; r < 4; r++) {
        int row = r0 + rt*16 + (l >> 4)*4 + r;
        float v = acc[rt][ci][r] + bias;
        if (outmode == 0) ((float*)out)[(size_t)row*out_ld + cl] = v;
        else ((unsigned short*)out)[(size_t)row*out_ld + cl] = f2h(v);
      }
  }
}

// ---------------- single-layer LSTM scan, fdot2 f16, 512 thr ---------------
// One block per batch element, one whh row per thread (64 packed-f16 uints,
// VGPR-resident). Best measured scan across the design space: 136.7 us
// (r11) vs occupancy x2 (neutral), 8-step global chunking (worse, r12),
// 16-batch MFMA tiling (2.8x worse at 16-block grid, r15). The floor is the
// dependent matvec+barrier+act chain at 256-block batch parallelism.
__global__ __launch_bounds__(512, 1) void k_lscan(
    const unsigned short* __restrict__ pre,   // f16 [B][T][512] (tstr=512) or [B][512] (tstr=0)
    const float* __restrict__ whh,
    const float* __restrict__ h0i, const float* __restrict__ c0i,
    int T, int tstr,
    unsigned short* __restrict__ ys,          // bf16 [B][T][128]
    float* __restrict__ hT, float* __restrict__ cT,
    unsigned short* __restrict__ hTb)         // bf16 [B][128]
{
  const int b = blockIdx.x, tid = threadIdx.x;
  unsigned int w[64];
  {
    const float* p0 = whh + (size_t)tid*128;
    #pragma unroll
    for (int k = 0; k < 64; k++) w[k] = pkh(p0[2*k], p0[2*k+1]);
  }
  __shared__ __align__(16) unsigned short hs[128];
  __shared__ float fg[512];
  float c = 0.f;
  if (tid < 128) {
    float h = h0i ? h0i[(size_t)b*128 + tid] : 0.f;
    c = c0i ? c0i[(size_t)b*128 + tid] : 0.f;
    hs[tid] = f2h(h);
  }
  __syncthreads();
  const unsigned short* preb = pre + (size_t)b * (tstr ? (size_t)T*tstr : 512);
  for (int t = 0; t < T; t++) {
    unsigned short p = preb[(size_t)t*tstr + tid];
    float a0 = 0.f, a1 = 0.f, a2 = 0.f, a3 = 0.f;
    #pragma unroll
    for (int k4 = 0; k4 < 16; k4++) {
      uint4 hh = *(const uint4*)&hs[k4*8];
      a0 = fd2(w[4*k4+0], hh.x, a0);
      a1 = fd2(w[4*k4+1], hh.y, a1);
      a2 = fd2(w[4*k4+2], hh.z, a2);
      a3 = fd2(w[4*k4+3], hh.w, a3);
    }
    fg[tid] = h2f(p) + (a0+a1) + (a2+a3);
    __syncthreads();
    if (tid < 128) {
      float iv = sigm (fg[tid]);
      float fv = sigm (fg[128 + tid]);
      float gv = tanhx(fg[256 + tid]);
      float ov = sigm (fg[384 + tid]);
      c = fv*c + iv*gv;
      float h = ov * tanhx(c);
      hs[tid] = f2h(h);
      ys[((size_t)b*T + t)*128 + tid] = f2bu(h);
      if (t == T-1) {
        hT[(size_t)b*128 + tid] = h;
        cT[(size_t)b*128 + tid] = c;
        hTb[(size_t)b*128 + tid] = f2bu(h);
      }
    }
    __syncthreads();
  }
}

// ---------------- cross attention: one block per (batch, head) -------------
__global__ __launch_bounds__(256) void k_attn(
    const float* __restrict__ Q, const float* __restrict__ K, const float* __restrict__ V,
    unsigned short* __restrict__ o)
{
  const int b = blockIdx.x, h = blockIdx.y, tid = threadIdx.x;
  __shared__ float Ks[168][33];
  __shared__ float Vs[168][32];
  __shared__ float Qs[24][32];
  __shared__ float Sc[24][169];
  __shared__ float red[24][8];
  __shared__ float rowm[24], rows[24];
  for (int e = tid; e < 168*32; e += 256) {
    int t = e >> 5, d = e & 31;
    Ks[t][d] = K[((size_t)b*168 + t)*128 + h*32 + d];
    Vs[t][d] = V[((size_t)b*168 + t)*128 + h*32 + d];
  }
  for (int e = tid; e < 24*32; e += 256) {
    int q = e >> 5, d = e & 31;
    Qs[q][d] = Q[((size_t)b*24 + q)*128 + h*32 + d];
  }
  __syncthreads();
  for (int e = tid; e < 24*168; e += 256) {
    int q = e / 168, t = e - q*168;
    float s = 0.f;
    #pragma unroll
    for (int d = 0; d < 32; d++) s += Qs[q][d]*Ks[t][d];
    Sc[q][t] = s * 0.17677669529663687f;
  }
  __syncthreads();
  int q = tid >> 3, l8 = tid & 7;
  if (q < 24) {
    float m = -1e30f;
    for (int t = l8; t < 168; t += 8) m = fmaxf(m, Sc[q][t]);
    red[q][l8] = m;
  }
  __syncthreads();
  if (q < 24 && l8 == 0) {
    float m = red[q][0];
    for (int p = 1; p < 8; p++) m = fmaxf(m, red[q][p]);
    rowm[q] = m;
  }
  __syncthreads();
  if (q < 24) {
    float s = 0.f;
    for (int t = l8; t < 168; t += 8) {
      float e2 = __expf(Sc[q][t] - rowm[q]);
      Sc[q][t] = e2; s += e2;
    }
    red[q][l8] = s;
  }
  __syncthreads();
  if (q < 24 && l8 == 0) {
    float s = 0.f;
    for (int p = 0; p < 8; p++) s += red[q][p];
    rows[q] = 1.f/s;
  }
  __syncthreads();
  for (int e = tid; e < 24*32; e += 256) {
    int qq = e >> 5, d = e & 31;
    float acc = 0.f;
    for (int t = 0; t < 168; t++) acc += Sc[qq][t]*Vs[t][d];
    o[((size_t)b*24 + qq)*128 + h*32 + d] = f2bu(acc * rows[qq]);
  }
}

// ---------------- post-attention GRN (MFMA, identity skip) -----------------
__global__ __launch_bounds__(256) void k_pa_mfma(
    const float* __restrict__ xin, const unsigned short* __restrict__ pk,
    const float* __restrict__ fc1_b, const float* __restrict__ fc2_b,
    const float* __restrict__ gate_b, const float* __restrict__ ln_g,
    const float* __restrict__ ln_b, float* __restrict__ out)
{
  const int n0 = blockIdx.x * 64;
  const int tid = threadIdx.x;
  const int wv = tid >> 6, l = tid & 63;
  __shared__ __align__(16) unsigned short As[64*136];
  __shared__ __align__(16) unsigned short A2s[64*136];
  __shared__ float xs[64*129];
  __shared__ float red[64][4][2];
  __shared__ float mr[64][2];
  for (int i2 = 0; i2 < 8; i2++) {
    int t4 = i2*256 + tid;
    int r = t4 >> 5, cc = (t4 & 31) << 2;
    float4 v = *(const float4*)(xin + (size_t)(n0 + r)*128 + cc);
    xs[r*129 + cc] = v.x; xs[r*129 + cc+1] = v.y;
    xs[r*129 + cc+2] = v.z; xs[r*129 + cc+3] = v.w;
    As[r*136 + cc] = f2bu(v.x); As[r*136 + cc+1] = f2bu(v.y);
    As[r*136 + cc+2] = f2bu(v.z); As[r*136 + cc+3] = f2bu(v.w);
  }
  __syncthreads();
  const unsigned short* W1 = pk + PK_PAF1;
  f32x4 acc1[4][2];
  #pragma unroll
  for (int rt = 0; rt < 4; rt++)
    #pragma unroll
    for (int ci = 0; ci < 2; ci++) acc1[rt][ci] = (f32x4)(0.f);
  #pragma unroll
  for (int kc = 0; kc < 4; kc++) {
    short8 af[4];
    #pragma unroll
    for (int rt = 0; rt < 4; rt++) {
      int row = rt*16 + (l & 15), g = kc*4 + (l >> 4);
      af[rt] = *(const short8*)&As[row*136 + g*8];
    }
    short8 bf[2];
    #pragma unroll
    for (int ci = 0; ci < 2; ci++) {
      int ct = wv*2 + ci;
      bf[ci] = *(const short8*)&W1[(((size_t)ct*4 + kc)*64 + l)*8];
    }
    #pragma unroll
    for (int rt = 0; rt < 4; rt++)
      #pragma unroll
      for (int ci = 0; ci < 2; ci++)
        acc1[rt][ci] = __builtin_amdgcn_mfma_f32_16x16x32_bf16(af[rt], bf[ci], acc1[rt][ci], 0, 0, 0);
  }
  __syncthreads();
  #pragma unroll
  for (int ci = 0; ci < 2; ci++) {
    int ch = wv*32 + ci*16 + (l & 15);
    float fb = fc1_b[ch];
    #pragma unroll
    for (int rt = 0; rt < 4; rt++)
      #pragma unroll
      for (int r = 0; r < 4; r++) {
        int row = rt*16 + (l >> 4)*4 + r;
        A2s[row*136 + ch] = f2bu(eluf(acc1[rt][ci][r] + fb));
      }
  }
  __syncthreads();
  const unsigned short* W2 = pk + PK_PAF2G;
  f32x4 acc2[4][4];
  #pragma unroll
  for (int rt = 0; rt < 4; rt++)
    #pragma unroll
    for (int ci = 0; ci < 4; ci++) acc2[rt][ci] = (f32x4)(0.f);
  #pragma unroll
  for (int kc = 0; kc < 4; kc++) {
    short8 af[4];
    #pragma unroll
    for (int rt = 0; rt < 4; rt++) {
      int row = rt*16 + (l & 15), g = kc*4 + (l >> 4);
      af[rt] = *(const short8*)&A2s[row*136 + g*8];
    }
    short8 bf[4];
    #pragma unroll
    for (int ci = 0; ci < 4; ci++) {
      int ct = (ci < 2) ? (wv*2 + ci) : (8 + wv*2 + (ci-2));
      bf[ci] = *(const short8*)&W2[(((size_t)ct*4 + kc)*64 + l)*8];
    }
    #pragma unroll
    for (int rt = 0; rt < 4; rt++)
      #pragma unroll
      for (int ci = 0; ci < 4; ci++)
        acc2[rt][ci] = __builtin_amdgcn_mfma_f32_16x16x32_bf16(af[rt], bf[ci], acc2[rt][ci], 0, 0, 0);
  }
  __syncthreads();
  #pragma unroll
  for (int ci = 0; ci < 2; ci++) {
    int ch = wv*32 + ci*16 + (l & 15);
    float f2 = fc2_b[ch], gb = gate_b[ch];
    #pragma unroll
    for (int rt = 0; rt < 4; rt++)
      #pragma unroll
      for (int r = 0; r < 4; r++) {
        int row = rt*16 + (l >> 4)*4 + r;
        float hv = acc2[rt][ci][r] + f2;
        float gv = sigm(acc2[rt][ci+2][r] + gb);
        xs[row*129 + ch] = xs[row*129 + ch] + hv*gv;
      }
  }
  __syncthreads();
  { int tk = tid >> 2, q = tid & 3;
    float s1 = 0.f, s2 = 0.f;
    #pragma unroll
    for (int i = 0; i < 32; i++) { float z = xs[tk*129 + q*32 + i]; s1 += z; s2 += z*z; }
    red[tk][q][0] = s1; red[tk][q][1] = s2;
  }
  __syncthreads();
  if ((tid & 3) == 0) {
    int tk = tid >> 2;
    float a = 0.f, b2 = 0.f;
    for (int p = 0; p < 4; p++) { a += red[tk][p][0]; b2 += red[tk][p][1]; }
    float mean = a * 0.0078125f;
    float var = b2 * 0.0078125f - mean*mean;
    mr[tk][0] = mean; mr[tk][1] = rsqrtf(fmaxf(var, 0.f) + 1e-5f);
  }
  __syncthreads();
  { int i = tid & 127;
    float lg = ln_g[i], lb = ln_b[i];
    for (int it = 0; it < 32; it++) {
      int tk = (tid >> 7) + it*2;
      out[(size_t)(n0+tk)*128 + i] = (xs[tk*129 + i] - mr[tk][0]) * mr[tk][1] * lg + lb;
    }
  }
}

// ---------------- final projection 128 -> 6 --------------------------------
__global__ __launch_bounds__(256) void k_final(
    const float* __restrict__ a, const float* __restrict__ fo_w,
    const float* __restrict__ fo_b, float* __restrict__ out)
{
  int idx = blockIdx.x*256 + threadIdx.x;
  if (idx >= NDTOK*6) return;
  int n = idx / 6, j = idx - n*6;
  const float* ar = a + (size_t)n*128;
  const float* w = fo_w + j*128;
  float s = fo_b[j];
  #pragma unroll 4
  for (int d = 0; d < 128; d++) s += ar[d]*w[d];
  out[idx] = s;
}

extern "C" void kernel_launch(void* const* d_in, const int* in_sizes, int n_in,
                              void* d_out, int out_size, void* d_ws, size_t ws_size,
                              hipStream_t stream) {
  (void)in_sizes; (void)n_in; (void)out_size; (void)ws_size;
  const float* x      = (const float*)d_in[0];
  const float* vfc1w  = (const float*)d_in[1];
  const float* vfc1b  = (const float*)d_in[2];
  const float* vfc2w  = (const float*)d_in[3];
  const float* vfc2b  = (const float*)d_in[4];
  const float* vgw    = (const float*)d_in[5];
  const float* vgb    = (const float*)d_in[6];
  const float* vskw   = (const float*)d_in[7];
  const float* vskb   = (const float*)d_in[8];
  const float* vlng   = (const float*)d_in[9];
  const float* vlnb   = (const float*)d_in[10];
  const float* gfc1w  = (const float*)d_in[11];
  const float* gfc1b  = (const float*)d_in[12];
  const float* gfc2w  = (const float*)d_in[13];
  const float* gfc2b  = (const float*)d_in[14];
  const float* ggw    = (const float*)d_in[15];
  const float* ggb    = (const float*)d_in[16];
  const float* gskw   = (const float*)d_in[17];
  const float* gskb   = (const float*)d_in[18];
  const float* glng   = (const float*)d_in[19];
  const float* glnb   = (const float*)d_in[20];
  const float* encwih = (const float*)d_in[21];
  const float* encwhh = (const float*)d_in[22];
  const float* encbih = (const float*)d_in[23];
  const float* encbhh = (const float*)d_in[24];
  const float* decwih = (const float*)d_in[25];
  const float* decwhh = (const float*)d_in[26];
  const float* decbih = (const float*)d_in[27];
  const float* decbhh = (const float*)d_in[28];
  const float* ainw   = (const float*)d_in[29];
  const float* ainb   = (const float*)d_in[30];
  const float* aoutw  = (const float*)d_in[31];
  const float* aoutb  = (const float*)d_in[32];
  const float* pfc1w  = (const float*)d_in[33];
  const float* pfc1b  = (const float*)d_in[34];
  const float* pfc2w  = (const float*)d_in[35];
  const float* pfc2b  = (const float*)d_in[36];
  const float* pgw    = (const float*)d_in[37];
  const float* pgb    = (const float*)d_in[38];
  const float* plng   = (const float*)d_in[39];
  const float* plnb   = (const float*)d_in[40];
  const float* fow    = (const float*)d_in[41];
  const float* fob    = (const float*)d_in[42];

  float* ws = (float*)d_ws;
  // ---- workspace (float offsets). Sizes: bf16/f16 [43008,128]=2,752,512 fl;
  // f16 [43008,512]=11,010,048 fl; proc2=24,772,608 fl; pk=999,424 us=499,712 fl.
  unsigned short* pk = (unsigned short*)ws;               // [0, 499,712)
  unsigned short* proc2 = (unsigned short*)(ws + 530000); // [530,000, 25,302,608)
  unsigned short* pre = (unsigned short*)(ws + 530000);   // f16 [43008][512] alias (proc2 dead) -> 11,540,048
  float* Kb   = ws + 530000;                              // f32 [43008,128] (pre dead) -> 6,035,024
  float* Vb   = ws + 6100000;                             // -> 11,605,024
  unsigned short* pre2 = (unsigned short*)(ws + 11700000);// f16 [6144,512] -> 13,272,864
  float* Qb   = ws + 13300000;                            // -> 14,086,432
  unsigned short* attb = (unsigned short*)(ws + 14100000);// -> 14,296,608
  float* ato  = ws + 14300000;                            // -> 15,086,432
  float* pao  = ws + 15100000;                            // -> 15,886,432
  unsigned short* pd0 = (unsigned short*)(ws + 15900000); // f16 [256,512] -> 15,965,536
  unsigned short* selb  = (unsigned short*)(ws + 25350000); // bf16 [43008,128] -> 28,102,512
  unsigned short* encob = (unsigned short*)(ws + 28150000); // bf16 [43008,128] -> 30,902,512
  unsigned short* ys0b  = (unsigned short*)(ws + 30950000); // bf16 [43008,128] -> 33,702,512
  unsigned short* dys0b = (unsigned short*)(ws + 33750000); // bf16 [6144,128] -> 33,946,608
  unsigned short* dout2b = (unsigned short*)(ws + 33950000);// bf16 [6144,128] -> 34,146,608
  float* hT0  = ws + 34150000;  float* cT0 = ws + 34190000;
  float* hT1  = ws + 34230000;  float* cT1 = ws + 34270000;
  unsigned short* hT1b = (unsigned short*)(ws + 34310000);  // bf16 [256,128]
  float* dscr = ws + 34350000;  // dummy hT/cT/hTb for scans that don't need them

  // 1. pack bf16 MFMA fragments
  k_pack<<<dim3(128, 9), dim3(256), 0, stream>>>(vfc2w, vgw, pk + PK_VSN, 128, 256, 128, 16384, 16384, 32768);
  k_pack<<<dim3(1152), dim3(256), 0, stream>>>(gfc1w, gskw, pk + PK_GC1, 1152, 256, 128, 0, 0, 0);
  k_pack<<<dim3(128), dim3(256), 0, stream>>>(gfc2w, ggw, pk + PK_GC2, 128, 256, 128, 0, 0, 0);
  k_pack<<<dim3(256), dim3(256), 0, stream>>>(encwih, encwih, pk + PK_ENC0, 128, 512, 512, 0, 0, 0);
  k_pack<<<dim3(256), dim3(256), 0, stream>>>(encwih + 65536, encwih, pk + PK_ENC1, 128, 512, 512, 0, 0, 0);
  k_pack<<<dim3(256), dim3(256), 0, stream>>>(decwih, decwih, pk + PK_DEC0, 128, 512, 512, 0, 0, 0);
  k_pack<<<dim3(256), dim3(256), 0, stream>>>(decwih + 65536, decwih, pk + PK_DEC1, 128, 512, 512, 0, 0, 0);
  k_pack<<<dim3(192), dim3(256), 0, stream>>>(ainw, ainw, pk + PK_AIN, 128, 384, 384, 0, 0, 0);
  k_pack<<<dim3(64), dim3(256), 0, stream>>>(aoutw, aoutw, pk + PK_AOUT, 128, 128, 128, 0, 0, 0);
  k_pack<<<dim3(64), dim3(256), 0, stream>>>(pfc1w, pfc1w, pk + PK_PAF1, 128, 128, 128, 0, 0, 0);
  k_pack<<<dim3(128), dim3(256), 0, stream>>>(pfc2w, pgw, pk + PK_PAF2G, 128, 256, 128, 0, 0, 0);
  // 2. VSN per-feature GRNs (MFMA)
  k_vsn_mfma<<<dim3(672, 9), dim3(256), 0, stream>>>(x, vfc1w, vfc1b, pk,
      vfc2b, vgb, vskw, vskb, vlng, vlnb, proc2);
  // 3. grand-selection GRN (MFMA, fused)
  k_gc_mfma<<<dim3(672), dim3(256), 0, stream>>>(proc2, pk, gfc1b, gfc2b, ggb,
      gskb, glng, glnb, selb);
  // 4. encoder layer 0: input projection (f16, biases folded) + scan
  k_mm<<<dim3(672, 4), dim3(256), 0, stream>>>(selb, pk + PK_ENC0, encbih, encbhh, pre, 512, 1);
  k_lscan<<<dim3(256), dim3(512), 0, stream>>>(pre, encwhh, nullptr, nullptr,
      TSE, 512, ys0b, hT0, cT0, (unsigned short*)dscr);
  // 5. encoder layer 1
  k_mm<<<dim3(672, 4), dim3(256), 0, stream>>>(ys0b, pk + PK_ENC1, encbih + 512, encbhh + 512, pre, 512, 1);
  k_lscan<<<dim3(256), dim3(512), 0, stream>>>(pre, encwhh + 65536, nullptr, nullptr,
      TSE, 512, encob, hT1, cT1, hT1b);
  // 6. decoder layer 0 (constant input hT1)
  k_mm<<<dim3(4, 4), dim3(256), 0, stream>>>(hT1b, pk + PK_DEC0, decbih, decbhh, pd0, 512, 1);
  k_lscan<<<dim3(256), dim3(512), 0, stream>>>(pd0, decwhh, hT0, cT0,
      TSD, 0, dys0b, dscr + 40000, dscr + 80000, (unsigned short*)dscr);
  // 7. decoder layer 1
  k_mm<<<dim3(96, 4), dim3(256), 0, stream>>>(dys0b, pk + PK_DEC1, decbih + 512, decbhh + 512, pre2, 512, 1);
  k_lscan<<<dim3(256), dim3(512), 0, stream>>>(pre2, decwhh + 65536, hT1, cT1,
      TSD, 512, dout2b, dscr + 120000, dscr + 160000, (unsigned short*)dscr);
  // 8. attention projections
  k_mm<<<dim3(96, 1), dim3(256), 0, stream>>>(dout2b, pk + PK_AIN, ainb, nullptr, Qb, 128, 0);
  k_mm<<<dim3(672, 1), dim3(256), 0, stream>>>(encob, pk + PK_AIN + 16384, ainb + 128, nullptr, Kb, 128, 0);
  k_mm<<<dim3(672, 1), dim3(256), 0, stream>>>(encob, pk + PK_AIN + 32768, ainb + 256, nullptr, Vb, 128, 0);
  // 9. attention core
  k_attn<<<dim3(256, 4), dim3(256), 0, stream>>>(Qb, Kb, Vb, attb);
  // 10. attention output projection
  k_mm<<<dim3(96, 1), dim3(256), 0, stream>>>(attb, pk + PK_AOUT, aoutb, nullptr, ato, 128, 0);
  // 11. post-attention GRN (MFMA)
  k_pa_mfma<<<dim3(96), dim3(256), 0, stream>>>(ato, pk, pfc1b, pfc2b, pgb,
      plng, plnb, pao);
  // 12. final projection
  k_final<<<dim3(144), dim3(256), 0, stream>>>(pao, fow, fob, (float*)d_out);
}